// Round 22
// baseline (32.425 us; speedup 1.0000x reference)
//
#include <hip/hip_runtime.h>
#include <hip/hip_bf16.h>

#define A_N 8192
#define LOG2E 1.44269504f

typedef __attribute__((ext_vector_type(8))) short short8v;
typedef __attribute__((ext_vector_type(4))) short short4v;
typedef __attribute__((ext_vector_type(4))) float f32x4;
typedef __attribute__((ext_vector_type(4))) int   i32x4;

__device__ inline short f2bf(float x) {
  unsigned u = __builtin_bit_cast(unsigned, x);
  unsigned r = (u + 0x7FFFu + ((u >> 16) & 1u)) >> 16;
  return (short)r;
}
__device__ inline float fexp2(float x) {
#if __has_builtin(__builtin_amdgcn_exp2f)
  return __builtin_amdgcn_exp2f(x);
#else
  return exp2f(x);
#endif
}
// Packed bf16 convert (RNE) via HIP intrinsic -> v_cvt_pk_bf16_f32, compiler-
// scheduled (hazard-safe). NOTE: never raw inline-asm feeding MFMA (R3-R5 bug).
__device__ inline unsigned cvtpk2(float lo, float hi) {
  float2 t; t.x = lo; t.y = hi;
  __hip_bfloat162 h = __float22bfloat162_rn(t);
  unsigned r; __builtin_memcpy(&r, &h, 4);
  return r;
}

// ---------------- K1: fused qkv (blocks 0..31) + conv partials (32..1567) ---------
// R21-verbatim.
__global__ __launch_bounds__(256) void fused_pre(
    const float* __restrict__ x, const float* __restrict__ cw,
    const float* __restrict__ cb, float* __restrict__ sfp,
    const int* __restrict__ act, const float* __restrict__ feat,
    const float* __restrict__ wq, const float* __restrict__ bq,
    const float* __restrict__ wk, const float* __restrict__ bk,
    const float* __restrict__ wv, const float* __restrict__ bv,
    const float* __restrict__ wo,
    short* __restrict__ Qo, short* __restrict__ Ko, short* __restrict__ V2S,
    int* __restrict__ counter) {
  __shared__ float swq[256], swk[256], swv[256], swo[256];
  __shared__ float sbq[16], sbk[16], sbv[16];
  __shared__ float red[4];
  int tid = threadIdx.x;
  if (blockIdx.x == 0 && tid == 0) *counter = 0;
  if (blockIdx.x >= 32) {
    int bid2 = blockIdx.x - 32;
    int u    = bid2 & 7;
    int base = bid2 >> 3;
    int b  = base & 1;
    int a  = (base >> 1) & 1;
    int ch = (base >> 2) & 15;
    int m  = base >> 6;
    float w00 = cw[ch*4+0], w01 = cw[ch*4+1], w10 = cw[ch*4+2], w11 = cw[ch*4+3];
    float bias = cb[ch];
    const float* xm = x + (size_t)m * 255 * 255;
    float sum = 0.f;
    #pragma unroll
    for (int it = 0; it < 8; ++it) {
      int p = u*2048 + it*256 + tid;
      int i = a*128 + (p >> 7);
      int j = b*128 + (p & 127);
      float x00 = (i >= 1 && j >= 1)   ? xm[(i-1)*255 + (j-1)] : 0.f;
      float x01 = (i >= 1 && j <= 254) ? xm[(i-1)*255 + j]     : 0.f;
      float x10 = (i <= 254 && j >= 1) ? xm[i*255 + (j-1)]     : 0.f;
      float x11 = (i <= 254 && j <= 254) ? xm[i*255 + j]       : 0.f;
      float v = fmaf(x00,w00, fmaf(x01,w01, fmaf(x10,w10, fmaf(x11,w11, bias))));
      sum += fmaxf(v, 0.f);
    }
    for (int o = 32; o; o >>= 1) sum += __shfl_down(sum, o, 64);
    int wid = tid >> 6, lane = tid & 63;
    if (lane == 0) red[wid] = sum;
    __syncthreads();
    if (tid == 0) sfp[bid2] = red[0]+red[1]+red[2]+red[3];
  } else {
    swq[tid] = wq[tid]; swk[tid] = wk[tid]; swv[tid] = wv[tid]; swo[tid] = wo[tid];
    if (tid < 16) { sbq[tid] = bq[tid]; sbk[tid] = bk[tid]; sbv[tid] = bv[tid]; }
    __syncthreads();
    int row = blockIdx.x * 256 + tid;
    int idx = act[row];
    const float4* f4 = (const float4*)(feat + (size_t)idx * 16);
    float4 a0 = f4[0], a1 = f4[1], a2 = f4[2], a3 = f4[3];
    float af[16] = {a0.x,a0.y,a0.z,a0.w, a1.x,a1.y,a1.z,a1.w,
                    a2.x,a2.y,a2.z,a2.w, a3.x,a3.y,a3.z,a3.w};
    float q[16], k[16], v[16];
    #pragma unroll
    for (int kk = 0; kk < 16; ++kk) {
      float aq = sbq[kk], ak = sbk[kk], av = sbv[kk];
      #pragma unroll
      for (int f = 0; f < 16; ++f) {
        aq = fmaf(af[f], swq[f*16+kk], aq);
        ak = fmaf(af[f], swk[f*16+kk], ak);
        av = fmaf(af[f], swv[f*16+kk], av);
      }
      q[kk] = aq; k[kk] = ak; v[kk] = av;
    }
    const float qs = 0.25f * LOG2E;
    int s  = row >> 5;
    int jj = row & 31;
    int hi = jj >> 4;
    int m2 = jj & 15;
    int gsw = m2 >> 2;
    int rsw = m2 & 3;
    size_t vbase = (size_t)s * 512 + (size_t)gsw * 128 + hi * 4 + rsw;
    // K paired-row swizzle: elem kk -> Ko[s*512 + (kk>>2)*128 + (jj&15)*8 + hi*4 + (kk&3)]
    size_t kbase = (size_t)s * 512 + (size_t)m2 * 8 + (size_t)hi * 4;
    #pragma unroll
    for (int kk = 0; kk < 16; ++kk) {
      float a = 0.f;
      #pragma unroll
      for (int f = 0; f < 16; ++f) a = fmaf(v[f], swo[f*16+kk], a);
      V2S[vbase + (size_t)kk * 8] = f2bf(a);
      Qo[(size_t)row*16 + kk] = f2bf(q[kk] * qs);
      Ko[kbase + (size_t)(kk >> 2) * 128 + (kk & 3)] = f2bf(k[kk]);
    }
  }
}

// ---------------- K2: attn + MLP + scores + (last block) final softmax ------------
// R21 structure; lsum now accumulated on the MATRIX pipe via mfma(P, ones, accl)
// (all B-entries 1.0 -> layout-independent row-sum), removing 16 VALU adds/step
// and the end-of-loop shuffles. li sums the same bf16 p values PV uses.
__global__ __launch_bounds__(1024, 1) void attn_score(
    const short* __restrict__ Qb, const short* __restrict__ Kb,
    const short* __restrict__ V2S, const float* __restrict__ sfp,
    const float* __restrict__ w1, const float* __restrict__ b1,
    const float* __restrict__ bo, const float* __restrict__ w2,
    float* __restrict__ scores, int* __restrict__ counter,
    float* __restrict__ outp) {
  __shared__ float sacc[16][32][16];
  __shared__ float sl[16][32];
  __shared__ float sw1[256];
  __shared__ float scvp[16][16];
  __shared__ float scv[16], sw2s[16];
  __shared__ float red2[16];
  __shared__ float sbc2[2];
  __shared__ int slastS;
  int tid = threadIdx.x;
  if (tid < 256) {
    sw1[tid] = w1[192*16 + tid];
    int c4 = tid >> 4, kq = tid & 15;
    float acc = (c4 == 0) ? b1[kq] : 0.f;
    #pragma unroll
    for (int si = 0; si < 12; ++si) {
      int s = c4*12 + si;
      const float* pp = sfp + s*8;
      float sv = ((pp[0]+pp[1])+(pp[2]+pp[3])) + ((pp[4]+pp[5])+(pp[6]+pp[7]));
      acc = fmaf(sv * (1.0f/16384.0f), w1[s*16+kq], acc);
    }
    if (c4 == 1) {
      #pragma unroll
      for (int f = 0; f < 16; ++f) acc = fmaf(bo[f], w1[(192+f)*16+kq], acc);
    }
    scvp[c4][kq] = acc;
  }
  if (tid < 16) sw2s[tid] = w2[tid];
  int w = tid >> 6, lane = tid & 63;
  int g = lane >> 4, fi = lane & 15;
  int i0 = blockIdx.x * 32;

  // exact-width Q fragments: all 64 lanes real (row=fi, k=g*4..g*4+3)
  short4v qfa = *(const short4v*)(Qb + (size_t)(i0 + fi)*16 + g*4);
  short4v qfb = *(const short4v*)(Qb + (size_t)(i0 + 16 + fi)*16 + g*4);
  const short* kp = Kb + (size_t)w*8192 + (size_t)lane*8;   // paired-row swizzled
  const short* vp = V2S + (size_t)(w*1024 + lane)*8;

  f32x4 acca = {0.f,0.f,0.f,0.f}, accb = {0.f,0.f,0.f,0.f};
  f32x4 accla = {0.f,0.f,0.f,0.f}, acclb = {0.f,0.f,0.f,0.f};
  const short onev = (short)0x3F80;   // bf16 1.0
  short8v ones8 = {onev,onev,onev,onev,onev,onev,onev,onev};

  // depth-2 prefetch pipeline (cur / nxt / nn), one dwordx4 each for K and V
  i32x4 kvc = *(const i32x4*)(kp);
  i32x4 vvc = *(const i32x4*)(vp);
  i32x4 kvx = *(const i32x4*)(kp + 512);
  i32x4 vvx = *(const i32x4*)(vp + 512);

  #pragma unroll
  for (int step = 0; step < 16; ++step) {
    i32x4 kvn = {0,0,0,0}, vvn = {0,0,0,0};
    if (step < 14) {
      kvn = *(const i32x4*)(kp + 1024);
      vvn = *(const i32x4*)(vp + 1024);
    }
    short8v kw = __builtin_bit_cast(short8v, kvc);
    short4v k0c = {kw[0], kw[1], kw[2], kw[3]};
    short4v k1c = {kw[4], kw[5], kw[6], kw[7]};
    short8v vf = __builtin_bit_cast(short8v, vvc);
    f32x4 zero4 = {0.f,0.f,0.f,0.f};
    f32x4 e0a = __builtin_amdgcn_mfma_f32_16x16x16bf16_1k(k0c, qfa, zero4, 0, 0, 0);
    f32x4 e1a = __builtin_amdgcn_mfma_f32_16x16x16bf16_1k(k1c, qfa, zero4, 0, 0, 0);
    f32x4 e0b = __builtin_amdgcn_mfma_f32_16x16x16bf16_1k(k0c, qfb, zero4, 0, 0, 0);
    f32x4 e1b = __builtin_amdgcn_mfma_f32_16x16x16bf16_1k(k1c, qfb, zero4, 0, 0, 0);
    {
      float p0 = fexp2(e0a[0]), p1 = fexp2(e0a[1]), p2 = fexp2(e0a[2]), p3 = fexp2(e0a[3]);
      float p4 = fexp2(e1a[0]), p5 = fexp2(e1a[1]), p6 = fexp2(e1a[2]), p7 = fexp2(e1a[3]);
      i32x4 pk;
      pk[0] = (int)cvtpk2(p0, p1); pk[1] = (int)cvtpk2(p2, p3);
      pk[2] = (int)cvtpk2(p4, p5); pk[3] = (int)cvtpk2(p6, p7);
      short8v pa = __builtin_bit_cast(short8v, pk);
      acca  = __builtin_amdgcn_mfma_f32_16x16x32_bf16(pa, vf, acca, 0, 0, 0);
      accla = __builtin_amdgcn_mfma_f32_16x16x32_bf16(pa, ones8, accla, 0, 0, 0);
    }
    {
      float p0 = fexp2(e0b[0]), p1 = fexp2(e0b[1]), p2 = fexp2(e0b[2]), p3 = fexp2(e0b[3]);
      float p4 = fexp2(e1b[0]), p5 = fexp2(e1b[1]), p6 = fexp2(e1b[2]), p7 = fexp2(e1b[3]);
      i32x4 pk;
      pk[0] = (int)cvtpk2(p0, p1); pk[1] = (int)cvtpk2(p2, p3);
      pk[2] = (int)cvtpk2(p4, p5); pk[3] = (int)cvtpk2(p6, p7);
      short8v pb = __builtin_bit_cast(short8v, pk);
      accb  = __builtin_amdgcn_mfma_f32_16x16x32_bf16(pb, vf, accb, 0, 0, 0);
      acclb = __builtin_amdgcn_mfma_f32_16x16x32_bf16(pb, ones8, acclb, 0, 0, 0);
    }
    kvc = kvx; vvc = vvx;
    kvx = kvn; vvx = vvn;
    kp += 512;
    vp += 512;
  }
  #pragma unroll
  for (int r = 0; r < 4; ++r) {
    sacc[w][4*g + r][fi]      = acca[r];
    sacc[w][16 + 4*g + r][fi] = accb[r];
  }
  if (fi == 0) {
    #pragma unroll
    for (int r = 0; r < 4; ++r) {
      sl[w][4*g + r]      = accla[r];
      sl[w][16 + 4*g + r] = acclb[r];
    }
  }
  __syncthreads();
  if (tid < 512) {
    int i = tid >> 4, f = tid & 15;
    float o = 0.f, li = 0.f;
    #pragma unroll
    for (int wv = 0; wv < 16; ++wv) { o += sacc[wv][i][f]; li += sl[wv][i]; }
    sacc[0][i][f] = o / li;
  } else if (tid < 528) {
    int k = tid - 512;
    float s = 0.f;
    #pragma unroll
    for (int c = 0; c < 16; ++c) s += scvp[c][k];
    scv[k] = s;
  }
  __syncthreads();
  if (tid < 512) {
    int i = tid >> 4, k = tid & 15;
    float h = scv[k];
    #pragma unroll
    for (int f = 0; f < 16; ++f) h = fmaf(sacc[0][i][f], sw1[f*16+k], h);
    h = fmaxf(h, 0.f);
    float t = h * sw2s[k];
    t += __shfl_xor(t, 1, 64);
    t += __shfl_xor(t, 2, 64);
    t += __shfl_xor(t, 4, 64);
    t += __shfl_xor(t, 8, 64);
    if (k == 0)
      __hip_atomic_store(&scores[i0 + i], t, __ATOMIC_RELAXED, __HIP_MEMORY_SCOPE_AGENT);
  }
  __syncthreads();
  if (tid == 0)
    slastS = __hip_atomic_fetch_add(counter, 1, __ATOMIC_ACQ_REL, __HIP_MEMORY_SCOPE_AGENT);
  __syncthreads();
  if (slastS != (A_N/32) - 1) return;

  float sv[8];
  #pragma unroll
  for (int u = 0; u < 8; ++u)
    sv[u] = __hip_atomic_load(&scores[tid + u*1024], __ATOMIC_RELAXED, __HIP_MEMORY_SCOPE_AGENT);
  int lane2 = tid & 63, wid2 = tid >> 6;
  float m = -3.4e38f;
  #pragma unroll
  for (int u = 0; u < 8; ++u) m = fmaxf(m, sv[u]);
  for (int o = 32; o; o >>= 1) m = fmaxf(m, __shfl_down(m, o, 64));
  if (lane2 == 0) red2[wid2] = m;
  __syncthreads();
  if (tid == 0) {
    float mm = red2[0];
    for (int wv = 1; wv < 16; ++wv) mm = fmaxf(mm, red2[wv]);
    sbc2[0] = mm;
  }
  __syncthreads();
  float mx = sbc2[0];
  float s = 0.f;
  #pragma unroll
  for (int u = 0; u < 8; ++u) s += __expf(sv[u] - mx);
  for (int o = 32; o; o >>= 1) s += __shfl_down(s, o, 64);
  if (lane2 == 0) red2[wid2] = s;
  __syncthreads();
  if (tid == 0) {
    float ss = 0.f;
    for (int wv = 0; wv < 16; ++wv) ss += red2[wv];
    sbc2[1] = ss;
  }
  __syncthreads();
  float inv = 1.0f / sbc2[1];
  #pragma unroll
  for (int u = 0; u < 8; ++u)
    outp[tid + u*1024] = __expf(sv[u] - mx) * inv;
}

extern "C" void kernel_launch(void* const* d_in, const int* in_sizes, int n_in,
                              void* d_out, int out_size, void* d_ws, size_t ws_size,
                              hipStream_t stream) {
  const float* x      = (const float*)d_in[0];
  const int*   act    = (const int*)  d_in[1];
  const float* feat   = (const float*)d_in[2];
  const float* conv_w = (const float*)d_in[3];
  const float* conv_b = (const float*)d_in[4];
  const float* wq     = (const float*)d_in[5];
  const float* bq     = (const float*)d_in[6];
  const float* wk     = (const float*)d_in[7];
  const float* bk     = (const float*)d_in[8];
  const float* wv     = (const float*)d_in[9];
  const float* bv     = (const float*)d_in[10];
  const float* wo     = (const float*)d_in[11];
  const float* bo     = (const float*)d_in[12];
  const float* w1     = (const float*)d_in[13];
  const float* b1     = (const float*)d_in[14];
  const float* w2     = (const float*)d_in[15];
  // d_in[16] = mlp_b2: softmax shift-invariant, dropped.

  char* wsb = (char*)d_ws;
  float* sfp    = (float*)(wsb);             // 1536 conv partials
  int*   ctr    = (int*)  (wsb + 8192);      // completion counter
  float* scores = (float*)(wsb + 16384);     // 8192 floats
  short* Qb     = (short*)(wsb + 65536);             // 8192*16 bf16
  short* Kb     = (short*)(wsb + 65536 + 262144);    // 8192*16 bf16 (pair-swizzled)
  short* V2S    = (short*)(wsb + 65536 + 524288);    // 8192*16 bf16 (swizzled)
  float* out    = (float*)d_out;

  fused_pre  <<<1568, 256, 0, stream>>>(x, conv_w, conv_b, sfp,
                                        act, feat, wq, bq, wk, bk, wv, bv, wo,
                                        Qb, Kb, V2S, ctr);
  attn_score <<<A_N/32, 1024, 0, stream>>>(Qb, Kb, V2S, sfp, w1, b1, bo, w2,
                                           scores, ctr, out);
}

// Round 23
// 31.374 us; speedup vs baseline: 1.0335x; 1.0335x over previous
//
#include <hip/hip_runtime.h>
#include <hip/hip_bf16.h>

#define A_N 8192
#define LOG2E 1.44269504f

typedef __attribute__((ext_vector_type(8))) short short8v;
typedef __attribute__((ext_vector_type(4))) short short4v;
typedef __attribute__((ext_vector_type(4))) float f32x4;
typedef __attribute__((ext_vector_type(4))) int   i32x4;

__device__ inline short f2bf(float x) {
  unsigned u = __builtin_bit_cast(unsigned, x);
  unsigned r = (u + 0x7FFFu + ((u >> 16) & 1u)) >> 16;
  return (short)r;
}
__device__ inline float fexp2(float x) {
#if __has_builtin(__builtin_amdgcn_exp2f)
  return __builtin_amdgcn_exp2f(x);
#else
  return exp2f(x);
#endif
}
// Packed bf16 convert (RNE) via HIP intrinsic -> v_cvt_pk_bf16_f32, compiler-
// scheduled (hazard-safe). NOTE: never raw inline-asm feeding MFMA (R3-R5 bug).
__device__ inline unsigned cvtpk2(float lo, float hi) {
  float2 t; t.x = lo; t.y = hi;
  __hip_bfloat162 h = __float22bfloat162_rn(t);
  unsigned r; __builtin_memcpy(&r, &h, 4);
  return r;
}

// ---------------- K1: fused qkv (blocks 0..31) + conv partials (32..1567) ---------
// R21-verbatim.
__global__ __launch_bounds__(256) void fused_pre(
    const float* __restrict__ x, const float* __restrict__ cw,
    const float* __restrict__ cb, float* __restrict__ sfp,
    const int* __restrict__ act, const float* __restrict__ feat,
    const float* __restrict__ wq, const float* __restrict__ bq,
    const float* __restrict__ wk, const float* __restrict__ bk,
    const float* __restrict__ wv, const float* __restrict__ bv,
    const float* __restrict__ wo,
    short* __restrict__ Qo, short* __restrict__ Ko, short* __restrict__ V2S,
    int* __restrict__ counter) {
  __shared__ float swq[256], swk[256], swv[256], swo[256];
  __shared__ float sbq[16], sbk[16], sbv[16];
  __shared__ float red[4];
  int tid = threadIdx.x;
  if (blockIdx.x == 0 && tid == 0) *counter = 0;
  if (blockIdx.x >= 32) {
    int bid2 = blockIdx.x - 32;
    int u    = bid2 & 7;
    int base = bid2 >> 3;
    int b  = base & 1;
    int a  = (base >> 1) & 1;
    int ch = (base >> 2) & 15;
    int m  = base >> 6;
    float w00 = cw[ch*4+0], w01 = cw[ch*4+1], w10 = cw[ch*4+2], w11 = cw[ch*4+3];
    float bias = cb[ch];
    const float* xm = x + (size_t)m * 255 * 255;
    float sum = 0.f;
    #pragma unroll
    for (int it = 0; it < 8; ++it) {
      int p = u*2048 + it*256 + tid;
      int i = a*128 + (p >> 7);
      int j = b*128 + (p & 127);
      float x00 = (i >= 1 && j >= 1)   ? xm[(i-1)*255 + (j-1)] : 0.f;
      float x01 = (i >= 1 && j <= 254) ? xm[(i-1)*255 + j]     : 0.f;
      float x10 = (i <= 254 && j >= 1) ? xm[i*255 + (j-1)]     : 0.f;
      float x11 = (i <= 254 && j <= 254) ? xm[i*255 + j]       : 0.f;
      float v = fmaf(x00,w00, fmaf(x01,w01, fmaf(x10,w10, fmaf(x11,w11, bias))));
      sum += fmaxf(v, 0.f);
    }
    for (int o = 32; o; o >>= 1) sum += __shfl_down(sum, o, 64);
    int wid = tid >> 6, lane = tid & 63;
    if (lane == 0) red[wid] = sum;
    __syncthreads();
    if (tid == 0) sfp[bid2] = red[0]+red[1]+red[2]+red[3];
  } else {
    swq[tid] = wq[tid]; swk[tid] = wk[tid]; swv[tid] = wv[tid]; swo[tid] = wo[tid];
    if (tid < 16) { sbq[tid] = bq[tid]; sbk[tid] = bk[tid]; sbv[tid] = bv[tid]; }
    __syncthreads();
    int row = blockIdx.x * 256 + tid;
    int idx = act[row];
    const float4* f4 = (const float4*)(feat + (size_t)idx * 16);
    float4 a0 = f4[0], a1 = f4[1], a2 = f4[2], a3 = f4[3];
    float af[16] = {a0.x,a0.y,a0.z,a0.w, a1.x,a1.y,a1.z,a1.w,
                    a2.x,a2.y,a2.z,a2.w, a3.x,a3.y,a3.z,a3.w};
    float q[16], k[16], v[16];
    #pragma unroll
    for (int kk = 0; kk < 16; ++kk) {
      float aq = sbq[kk], ak = sbk[kk], av = sbv[kk];
      #pragma unroll
      for (int f = 0; f < 16; ++f) {
        aq = fmaf(af[f], swq[f*16+kk], aq);
        ak = fmaf(af[f], swk[f*16+kk], ak);
        av = fmaf(af[f], swv[f*16+kk], av);
      }
      q[kk] = aq; k[kk] = ak; v[kk] = av;
    }
    const float qs = 0.25f * LOG2E;
    int s  = row >> 5;
    int jj = row & 31;
    int hi = jj >> 4;
    int m2 = jj & 15;
    int gsw = m2 >> 2;
    int rsw = m2 & 3;
    size_t vbase = (size_t)s * 512 + (size_t)gsw * 128 + hi * 4 + rsw;
    // K paired-row swizzle: elem kk -> Ko[s*512 + (kk>>2)*128 + (jj&15)*8 + hi*4 + (kk&3)]
    size_t kbase = (size_t)s * 512 + (size_t)m2 * 8 + (size_t)hi * 4;
    #pragma unroll
    for (int kk = 0; kk < 16; ++kk) {
      float a = 0.f;
      #pragma unroll
      for (int f = 0; f < 16; ++f) a = fmaf(v[f], swo[f*16+kk], a);
      V2S[vbase + (size_t)kk * 8] = f2bf(a);
      Qo[(size_t)row*16 + kk] = f2bf(q[kk] * qs);
      Ko[kbase + (size_t)(kk >> 2) * 128 + (kk & 3)] = f2bf(k[kk]);
    }
  }
}

// ---------------- K2: attn + MLP + scores + (last block) final softmax ------------
// R21-verbatim main loop/epilogue; final softmax simplified: scores are bounded
// (|s| <~ 5) so the max-shift is dropped (one reduction instead of two) and the
// exp values are cached in registers for the writeback.
__global__ __launch_bounds__(1024, 1) void attn_score(
    const short* __restrict__ Qb, const short* __restrict__ Kb,
    const short* __restrict__ V2S, const float* __restrict__ sfp,
    const float* __restrict__ w1, const float* __restrict__ b1,
    const float* __restrict__ bo, const float* __restrict__ w2,
    float* __restrict__ scores, int* __restrict__ counter,
    float* __restrict__ outp) {
  __shared__ float sacc[16][32][16];
  __shared__ float sl[16][32];
  __shared__ float sw1[256];
  __shared__ float scvp[16][16];
  __shared__ float scv[16], sw2s[16];
  __shared__ float red2[16];
  __shared__ float sbc2[2];
  __shared__ int slastS;
  int tid = threadIdx.x;
  if (tid < 256) {
    sw1[tid] = w1[192*16 + tid];
    int c4 = tid >> 4, kq = tid & 15;
    float acc = (c4 == 0) ? b1[kq] : 0.f;
    #pragma unroll
    for (int si = 0; si < 12; ++si) {
      int s = c4*12 + si;
      const float* pp = sfp + s*8;
      float sv = ((pp[0]+pp[1])+(pp[2]+pp[3])) + ((pp[4]+pp[5])+(pp[6]+pp[7]));
      acc = fmaf(sv * (1.0f/16384.0f), w1[s*16+kq], acc);
    }
    if (c4 == 1) {
      #pragma unroll
      for (int f = 0; f < 16; ++f) acc = fmaf(bo[f], w1[(192+f)*16+kq], acc);
    }
    scvp[c4][kq] = acc;
  }
  if (tid < 16) sw2s[tid] = w2[tid];
  int w = tid >> 6, lane = tid & 63;
  int g = lane >> 4, fi = lane & 15;
  int i0 = blockIdx.x * 32;

  // exact-width Q fragments: all 64 lanes real (row=fi, k=g*4..g*4+3)
  short4v qfa = *(const short4v*)(Qb + (size_t)(i0 + fi)*16 + g*4);
  short4v qfb = *(const short4v*)(Qb + (size_t)(i0 + 16 + fi)*16 + g*4);
  const short* kp = Kb + (size_t)w*8192 + (size_t)lane*8;   // paired-row swizzled
  const short* vp = V2S + (size_t)(w*1024 + lane)*8;

  f32x4 acca = {0.f,0.f,0.f,0.f}, accb = {0.f,0.f,0.f,0.f};
  float lsa = 0.f, lsb = 0.f;

  // depth-2 prefetch pipeline (cur / nxt / nn), one dwordx4 each for K and V
  i32x4 kvc = *(const i32x4*)(kp);
  i32x4 vvc = *(const i32x4*)(vp);
  i32x4 kvx = *(const i32x4*)(kp + 512);
  i32x4 vvx = *(const i32x4*)(vp + 512);

  #pragma unroll
  for (int step = 0; step < 16; ++step) {
    i32x4 kvn = {0,0,0,0}, vvn = {0,0,0,0};
    if (step < 14) {
      kvn = *(const i32x4*)(kp + 1024);
      vvn = *(const i32x4*)(vp + 1024);
    }
    short8v kw = __builtin_bit_cast(short8v, kvc);
    short4v k0c = {kw[0], kw[1], kw[2], kw[3]};
    short4v k1c = {kw[4], kw[5], kw[6], kw[7]};
    short8v vf = __builtin_bit_cast(short8v, vvc);
    f32x4 zero4 = {0.f,0.f,0.f,0.f};
    f32x4 e0a = __builtin_amdgcn_mfma_f32_16x16x16bf16_1k(k0c, qfa, zero4, 0, 0, 0);
    f32x4 e1a = __builtin_amdgcn_mfma_f32_16x16x16bf16_1k(k1c, qfa, zero4, 0, 0, 0);
    f32x4 e0b = __builtin_amdgcn_mfma_f32_16x16x16bf16_1k(k0c, qfb, zero4, 0, 0, 0);
    f32x4 e1b = __builtin_amdgcn_mfma_f32_16x16x16bf16_1k(k1c, qfb, zero4, 0, 0, 0);
    {
      float p0 = fexp2(e0a[0]), p1 = fexp2(e0a[1]), p2 = fexp2(e0a[2]), p3 = fexp2(e0a[3]);
      float p4 = fexp2(e1a[0]), p5 = fexp2(e1a[1]), p6 = fexp2(e1a[2]), p7 = fexp2(e1a[3]);
      lsa += ((p0+p1)+(p2+p3)) + ((p4+p5)+(p6+p7));
      i32x4 pk;
      pk[0] = (int)cvtpk2(p0, p1); pk[1] = (int)cvtpk2(p2, p3);
      pk[2] = (int)cvtpk2(p4, p5); pk[3] = (int)cvtpk2(p6, p7);
      acca = __builtin_amdgcn_mfma_f32_16x16x32_bf16(__builtin_bit_cast(short8v, pk), vf, acca, 0, 0, 0);
    }
    {
      float p0 = fexp2(e0b[0]), p1 = fexp2(e0b[1]), p2 = fexp2(e0b[2]), p3 = fexp2(e0b[3]);
      float p4 = fexp2(e1b[0]), p5 = fexp2(e1b[1]), p6 = fexp2(e1b[2]), p7 = fexp2(e1b[3]);
      lsb += ((p0+p1)+(p2+p3)) + ((p4+p5)+(p6+p7));
      i32x4 pk;
      pk[0] = (int)cvtpk2(p0, p1); pk[1] = (int)cvtpk2(p2, p3);
      pk[2] = (int)cvtpk2(p4, p5); pk[3] = (int)cvtpk2(p6, p7);
      accb = __builtin_amdgcn_mfma_f32_16x16x32_bf16(__builtin_bit_cast(short8v, pk), vf, accb, 0, 0, 0);
    }
    kvc = kvx; vvc = vvx;
    kvx = kvn; vvx = vvn;
    kp += 512;
    vp += 512;
  }
  lsa += __shfl_xor(lsa, 16, 64); lsa += __shfl_xor(lsa, 32, 64);
  lsb += __shfl_xor(lsb, 16, 64); lsb += __shfl_xor(lsb, 32, 64);
  #pragma unroll
  for (int r = 0; r < 4; ++r) {
    sacc[w][4*g + r][fi]      = acca[r];
    sacc[w][16 + 4*g + r][fi] = accb[r];
  }
  if (g == 0) { sl[w][fi] = lsa; sl[w][16 + fi] = lsb; }
  __syncthreads();
  if (tid < 512) {
    int i = tid >> 4, f = tid & 15;
    float o = 0.f, li = 0.f;
    #pragma unroll
    for (int wv = 0; wv < 16; ++wv) { o += sacc[wv][i][f]; li += sl[wv][i]; }
    sacc[0][i][f] = o / li;
  } else if (tid < 528) {
    int k = tid - 512;
    float s = 0.f;
    #pragma unroll
    for (int c = 0; c < 16; ++c) s += scvp[c][k];
    scv[k] = s;
  }
  __syncthreads();
  if (tid < 512) {
    int i = tid >> 4, k = tid & 15;
    float h = scv[k];
    #pragma unroll
    for (int f = 0; f < 16; ++f) h = fmaf(sacc[0][i][f], sw1[f*16+k], h);
    h = fmaxf(h, 0.f);
    float t = h * sw2s[k];
    t += __shfl_xor(t, 1, 64);
    t += __shfl_xor(t, 2, 64);
    t += __shfl_xor(t, 4, 64);
    t += __shfl_xor(t, 8, 64);
    if (k == 0)
      __hip_atomic_store(&scores[i0 + i], t, __ATOMIC_RELAXED, __HIP_MEMORY_SCOPE_AGENT);
  }
  __syncthreads();
  if (tid == 0)
    slastS = __hip_atomic_fetch_add(counter, 1, __ATOMIC_ACQ_REL, __HIP_MEMORY_SCOPE_AGENT);
  __syncthreads();
  if (slastS != (A_N/32) - 1) return;

  // ---- last block: final softmax (no max-shift; scores bounded |s|<~5) ----
  float ev[8];
  float s = 0.f;
  #pragma unroll
  for (int u = 0; u < 8; ++u) {
    float sv = __hip_atomic_load(&scores[tid + u*1024], __ATOMIC_RELAXED, __HIP_MEMORY_SCOPE_AGENT);
    ev[u] = __expf(sv);
    s += ev[u];
  }
  int lane2 = tid & 63, wid2 = tid >> 6;
  for (int o = 32; o; o >>= 1) s += __shfl_down(s, o, 64);
  if (lane2 == 0) red2[wid2] = s;
  __syncthreads();
  if (tid == 0) {
    float ss = 0.f;
    for (int wv = 0; wv < 16; ++wv) ss += red2[wv];
    sbc2[0] = ss;
  }
  __syncthreads();
  float inv = 1.0f / sbc2[0];
  #pragma unroll
  for (int u = 0; u < 8; ++u)
    outp[tid + u*1024] = ev[u] * inv;
}

extern "C" void kernel_launch(void* const* d_in, const int* in_sizes, int n_in,
                              void* d_out, int out_size, void* d_ws, size_t ws_size,
                              hipStream_t stream) {
  const float* x      = (const float*)d_in[0];
  const int*   act    = (const int*)  d_in[1];
  const float* feat   = (const float*)d_in[2];
  const float* conv_w = (const float*)d_in[3];
  const float* conv_b = (const float*)d_in[4];
  const float* wq     = (const float*)d_in[5];
  const float* bq     = (const float*)d_in[6];
  const float* wk     = (const float*)d_in[7];
  const float* bk     = (const float*)d_in[8];
  const float* wv     = (const float*)d_in[9];
  const float* bv     = (const float*)d_in[10];
  const float* wo     = (const float*)d_in[11];
  const float* bo     = (const float*)d_in[12];
  const float* w1     = (const float*)d_in[13];
  const float* b1     = (const float*)d_in[14];
  const float* w2     = (const float*)d_in[15];
  // d_in[16] = mlp_b2: softmax shift-invariant, dropped.

  char* wsb = (char*)d_ws;
  float* sfp    = (float*)(wsb);             // 1536 conv partials
  int*   ctr    = (int*)  (wsb + 8192);      // completion counter
  float* scores = (float*)(wsb + 16384);     // 8192 floats
  short* Qb     = (short*)(wsb + 65536);             // 8192*16 bf16
  short* Kb     = (short*)(wsb + 65536 + 262144);    // 8192*16 bf16 (pair-swizzled)
  short* V2S    = (short*)(wsb + 65536 + 524288);    // 8192*16 bf16 (swizzled)
  float* out    = (float*)d_out;

  fused_pre  <<<1568, 256, 0, stream>>>(x, conv_w, conv_b, sfp,
                                        act, feat, wq, bq, wk, bk, wv, bv, wo,
                                        Qb, Kb, V2S, ctr);
  attn_score <<<A_N/32, 1024, 0, stream>>>(Qb, Kb, V2S, sfp, w1, b1, bo, w2,
                                           scores, ctr, out);
}